// Round 7
// baseline (308.041 us; speedup 1.0000x reference)
//
#include <hip/hip_runtime.h>

#define TPB 256

// ---------------------------------------------------------------------------
// partial_activation: Y[32] viewed as 16 blocks of 2, M=2, Q=2.0.
// pos[b] = #(Y[2b..2b+1] > 0); minI/maxI = FIRST argmin/argmax of pos;
// mask: *2 on max block if pos==2, *0 on min block if pos==0.
// train += relu-sum of min block (if fails) + (-negsum) of max block (if fails).
// succ += (min_succ && max_succ).
// All indexing compile-time constant (rule #20) -> Y stays in VGPRs.
// IDENTICAL math/order to rounds 2/3/6 that passed (absmax 0.0039) --
// do NOT reassociate: mask decisions are sign-sensitive.
// ---------------------------------------------------------------------------
__device__ __forceinline__ void partial_act(float (&Y)[32], float& t_acc, int& s_cnt)
{
    int pos[16];
#pragma unroll
    for (int b = 0; b < 16; ++b)
        pos[b] = (Y[2 * b] > 0.0f ? 1 : 0) + (Y[2 * b + 1] > 0.0f ? 1 : 0);

    int minv = pos[0], maxv = pos[0];
    int minI = 0, maxI = 0;
    float ymin0 = Y[0], ymin1 = Y[1];
    float ymax0 = Y[0], ymax1 = Y[1];
#pragma unroll
    for (int b = 1; b < 16; ++b) {
        bool lt = pos[b] < minv;   // strict < keeps FIRST argmin (jnp.argmin)
        minv  = lt ? pos[b]       : minv;
        minI  = lt ? b            : minI;
        ymin0 = lt ? Y[2 * b]     : ymin0;
        ymin1 = lt ? Y[2 * b + 1] : ymin1;
        bool gt = pos[b] > maxv;   // strict > keeps FIRST argmax (jnp.argmax)
        maxv  = gt ? pos[b]       : maxv;
        maxI  = gt ? b            : maxI;
        ymax0 = gt ? Y[2 * b]     : ymax0;
        ymax1 = gt ? Y[2 * b + 1] : ymax1;
    }
    bool min_succ = (minv == 0);
    bool max_succ = (maxv == 2);

    // train uses PRE-mask Y: y*(y>0)==max(y,0); -y*(y<0)==-min(y,0)
    float cmin = fmaxf(ymin0, 0.0f) + fmaxf(ymin1, 0.0f);
    float cmax = -(fminf(ymax0, 0.0f) + fminf(ymax1, 0.0f));
    t_acc += (min_succ ? 0.0f : cmin) + (max_succ ? 0.0f : cmax);
    s_cnt += (min_succ && max_succ) ? 1 : 0;

#pragma unroll
    for (int b = 0; b < 16; ++b) {
        bool ismax = max_succ && (b == maxI);
        bool ismin = min_succ && (b == minI);
        float mfac = ismax ? 2.0f : 1.0f;
        mfac = ismin ? 0.0f : mfac;
        Y[2 * b]     *= mfac;
        Y[2 * b + 1] *= mfac;
    }
}

// per-row layer 3 + softmax + store (order identical to round 6 per row)
__device__ __forceinline__ void l3_softmax_store(
    const float (&Z)[32], const float* __restrict__ W3,
    const float* __restrict__ b3, float2* __restrict__ out2, int r)
{
    float z0 = b3[0], z1 = b3[1];
#pragma unroll
    for (int k = 0; k < 32; ++k) {
        z0 = fmaf(Z[k], W3[k], z0);
        z1 = fmaf(Z[k], W3[32 + k], z1);
    }
    float m  = fmaxf(z0, z1);
    float e0 = __expf(z0 - m);
    float e1 = __expf(z1 - m);
    float iv = 1.0f / (e0 + e1);
    float2 o; o.x = e0 * iv; o.y = e1 * iv;
    out2[r] = o;
}

// ---------------------------------------------------------------------------
// Round-7 structure: FOUR rows per thread (r0 + q*quarter), j-outer layer 2.
// Rationale: SMEM (s_load) returns out-of-order -> compiler must drain
// lgkmcnt(0) before each j-step's FMAs; that latency is un-hideable by
// pipelining, so amortize it over 4 independent fma chains (256 VALU cycles
// per j vs ~100-200 cyc latency) and halve per-row weight traffic again.
// ~280-310 VGPRs expected (unified VGPR/AGPR file, no spill through 450 —
// m08/m24); __launch_bounds__(256,1) lifts the regalloc cap to 512.
// Per-row fma chain order is bit-identical to rounds 2/3/6.
// ---------------------------------------------------------------------------
__global__ __launch_bounds__(TPB, 1) void net_main(
    const float* __restrict__ x,
    const float* __restrict__ W1, const float* __restrict__ b1,
    const float* __restrict__ W2, const float* __restrict__ b2,
    const float* __restrict__ W3, const float* __restrict__ b3,
    float* __restrict__ out,
    float* __restrict__ t_part, int* __restrict__ c_part,
    unsigned* __restrict__ counter,
    int quarter, int nrows, double inv_denom)
{
    const int tid = threadIdx.x;
    const int r0  = blockIdx.x * TPB + tid;

    float t_acc = 0.0f;
    int   s_cnt = 0;

    if (r0 < quarter) {
        const float2* x2 = reinterpret_cast<const float2*>(x);
        float2* out2     = reinterpret_cast<float2*>(out);
        const int r1 = r0 + quarter, r2 = r0 + 2 * quarter, r3 = r0 + 3 * quarter;
        const float2 xa = x2[r0];
        const float2 xb = x2[r1];
        const float2 xc = x2[r2];
        const float2 xd = x2[r3];

        // ---- layer 1 for all four rows (weights uniform -> SGPR) ----
        float A[32], B[32], C[32], D[32];
#pragma unroll
        for (int j = 0; j < 32; ++j) {
            const float w0 = W1[2 * j], w1 = W1[2 * j + 1], bb = b1[j];
            A[j] = fmaf(xa.y, w1, fmaf(xa.x, w0, bb));
            B[j] = fmaf(xb.y, w1, fmaf(xb.x, w0, bb));
            C[j] = fmaf(xc.y, w1, fmaf(xc.x, w0, bb));
            D[j] = fmaf(xd.y, w1, fmaf(xd.x, w0, bb));
        }

        partial_act(A, t_acc, s_cnt);
        partial_act(B, t_acc, s_cnt);
        partial_act(C, t_acc, s_cnt);
        partial_act(D, t_acc, s_cnt);

        // ---- layer 2, j-outer: W2 row j is 32 contiguous floats in SGPRs;
        //      4 independent ascending-k fma chains per j (ILP=4) ----
        float ZA[32], ZB[32], ZC[32], ZD[32];
#pragma unroll
        for (int j = 0; j < 32; ++j) {
            float a0 = b2[j];
            float a1 = b2[j];
            float a2 = b2[j];
            float a3 = b2[j];
#pragma unroll
            for (int k = 0; k < 32; ++k) {
                const float w = W2[32 * j + k];   // uniform -> SGPR operand
                a0 = fmaf(A[k], w, a0);           // exact same per-row chain
                a1 = fmaf(B[k], w, a1);           //  order as rounds 2/3/6
                a2 = fmaf(C[k], w, a2);
                a3 = fmaf(D[k], w, a3);
            }
            ZA[j] = a0; ZB[j] = a1; ZC[j] = a2; ZD[j] = a3;
        }

        partial_act(ZA, t_acc, s_cnt);
        partial_act(ZB, t_acc, s_cnt);
        partial_act(ZC, t_acc, s_cnt);
        partial_act(ZD, t_acc, s_cnt);

        // ---- layer 3 + softmax + store, each row ----
        l3_softmax_store(ZA, W3, b3, out2, r0);
        l3_softmax_store(ZB, W3, b3, out2, r1);
        l3_softmax_store(ZC, W3, b3, out2, r2);
        l3_softmax_store(ZD, W3, b3, out2, r3);
    }

    // ---- block reduction: wave shuffle -> LDS -> per-block partial ----
#pragma unroll
    for (int off = 32; off; off >>= 1) {
        t_acc += __shfl_down(t_acc, off);
        s_cnt += __shfl_down(s_cnt, off);
    }
    __shared__ float ts[TPB / 64];
    __shared__ int   cs[TPB / 64];
    __shared__ bool  amLast;
    const int wid  = tid >> 6;
    const int lane = tid & 63;
    if (lane == 0) { ts[wid] = t_acc; cs[wid] = s_cnt; }
    __syncthreads();
    if (tid == 0) {
        float tt = ts[0];
        int   cc = cs[0];
#pragma unroll
        for (int w = 1; w < TPB / 64; ++w) { tt += ts[w]; cc += cs[w]; }
        t_part[blockIdx.x] = tt;
        c_part[blockIdx.x] = cc;
        __threadfence();                        // partials visible device-wide
        unsigned old = atomicAdd(counter, 1u);  // device-scope by default
        amLast = (old == gridDim.x - 1);
    }
    __syncthreads();

    // ---- last block reduces all partials (fixed order -> deterministic) ----
    if (amLast) {
        __threadfence();
        double t = 0.0;
        int    c = 0;
        const int nparts = gridDim.x;
        for (int i = tid; i < nparts; i += TPB) {
            t += (double)t_part[i];
            c += c_part[i];
        }
#pragma unroll
        for (int off = 32; off; off >>= 1) {
            t += __shfl_down(t, off);
            c += __shfl_down(c, off);
        }
        __shared__ double td[TPB / 64];
        __shared__ int    cd[TPB / 64];
        if (lane == 0) { td[wid] = t; cd[wid] = c; }
        __syncthreads();
        if (tid == 0) {
            double tt = 0.0;
            int    cc = 0;
#pragma unroll
            for (int w = 0; w < TPB / 64; ++w) { tt += td[w]; cc += cd[w]; }
            float* scal = out + (size_t)nrows * 2;
            scal[0] = (float)((double)cc * inv_denom); // succ = cnt / (2B)
            scal[1] = (float)tt;                       // train = t1 + t2
        }
    }
}

extern "C" void kernel_launch(void* const* d_in, const int* in_sizes, int n_in,
                              void* d_out, int out_size, void* d_ws, size_t ws_size,
                              hipStream_t stream)
{
    const float* x  = (const float*)d_in[0];
    const float* W1 = (const float*)d_in[1];
    const float* b1 = (const float*)d_in[2];
    const float* W2 = (const float*)d_in[3];
    const float* b2 = (const float*)d_in[4];
    const float* W3 = (const float*)d_in[5];
    const float* b3 = (const float*)d_in[6];
    float* out = (float*)d_out;

    const int nrows   = in_sizes[0] / 2;            // B = 1048576 (divisible by 4)
    const int quarter = nrows / 4;                  // 4 rows per thread
    const int nblocks = (quarter + TPB - 1) / TPB;  // 1024

    float*    t_part  = (float*)d_ws;
    int*      c_part  = (int*)((char*)d_ws + (size_t)nblocks * sizeof(float));
    unsigned* counter = (unsigned*)((char*)d_ws + (size_t)nblocks * 2 * sizeof(float));

    // ws is poisoned 0xAA before every timed launch -> zero the done-counter.
    hipMemsetAsync(counter, 0, sizeof(unsigned), stream);

    net_main<<<nblocks, TPB, 0, stream>>>(x, W1, b1, W2, b2, W3, b3,
                                          out, t_part, c_part, counter,
                                          quarter, nrows, 1.0 / (2.0 * (double)nrows));
}

// Round 8
// 202.388 us; speedup vs baseline: 1.5220x; 1.5220x over previous
//
#include <hip/hip_runtime.h>

#define TPB 256

// ---------------------------------------------------------------------------
// partial_activation: Y[32] viewed as 16 blocks of 2, M=2, Q=2.0.
// pos[b] = #(Y[2b..2b+1] > 0); minI/maxI = FIRST argmin/argmax of pos;
// mask: *2 on max block if pos==2, *0 on min block if pos==0.
// train += relu-sum of min block (if fails) + (-negsum) of max block (if fails).
// succ += (min_succ && max_succ).
// All indexing compile-time constant (rule #20) -> Y stays in VGPRs.
// IDENTICAL math/order to rounds 2/3/6 that passed (absmax 0.0039) --
// do NOT reassociate: mask decisions are sign-sensitive.
// ---------------------------------------------------------------------------
__device__ __forceinline__ void partial_act(float (&Y)[32], float& t_acc, int& s_cnt)
{
    int pos[16];
#pragma unroll
    for (int b = 0; b < 16; ++b)
        pos[b] = (Y[2 * b] > 0.0f ? 1 : 0) + (Y[2 * b + 1] > 0.0f ? 1 : 0);

    int minv = pos[0], maxv = pos[0];
    int minI = 0, maxI = 0;
    float ymin0 = Y[0], ymin1 = Y[1];
    float ymax0 = Y[0], ymax1 = Y[1];
#pragma unroll
    for (int b = 1; b < 16; ++b) {
        bool lt = pos[b] < minv;   // strict < keeps FIRST argmin (jnp.argmin)
        minv  = lt ? pos[b]       : minv;
        minI  = lt ? b            : minI;
        ymin0 = lt ? Y[2 * b]     : ymin0;
        ymin1 = lt ? Y[2 * b + 1] : ymin1;
        bool gt = pos[b] > maxv;   // strict > keeps FIRST argmax (jnp.argmax)
        maxv  = gt ? pos[b]       : maxv;
        maxI  = gt ? b            : maxI;
        ymax0 = gt ? Y[2 * b]     : ymax0;
        ymax1 = gt ? Y[2 * b + 1] : ymax1;
    }
    bool min_succ = (minv == 0);
    bool max_succ = (maxv == 2);

    // train uses PRE-mask Y: y*(y>0)==max(y,0); -y*(y<0)==-min(y,0)
    float cmin = fmaxf(ymin0, 0.0f) + fmaxf(ymin1, 0.0f);
    float cmax = -(fminf(ymax0, 0.0f) + fminf(ymax1, 0.0f));
    t_acc += (min_succ ? 0.0f : cmin) + (max_succ ? 0.0f : cmax);
    s_cnt += (min_succ && max_succ) ? 1 : 0;

#pragma unroll
    for (int b = 0; b < 16; ++b) {
        bool ismax = max_succ && (b == maxI);
        bool ismin = min_succ && (b == minI);
        float mfac = ismax ? 2.0f : 1.0f;
        mfac = ismin ? 0.0f : mfac;
        Y[2 * b]     *= mfac;
        Y[2 * b + 1] *= mfac;
    }
}

// ---------------------------------------------------------------------------
// Round-8 structure: R=2 rows/thread (round-6 anchor, 87us) with ONE change:
// W2 is read through the VECTOR memory pipe instead of SMEM.
//   Why: SMEM returns out-of-order -> only lgkmcnt(0) is usable -> a wait on
//   row j's weights also drains row j+1's prefetch -> per-j serialization
//   (~180cy K$ latency exposed against 128cy of fma; busy 51%). VMEM vmcnt is
//   IN-ORDER, so the scheduler can hoist next rows' global_load_dwordx4 above
//   the current row's fmas and wait vmcnt(N>0) -> latency hidden. W2 is 4KB,
//   L1-resident; same-address loads broadcast from one cache line.
//   The opaque asm zero makes the address formally divergent so hipcc cannot
//   scalarize the loads back to s_load (it proves uniformity otherwise).
// Per-row fma chain order remains bit-identical to rounds 2/3/6.
// ---------------------------------------------------------------------------
__global__ __launch_bounds__(TPB, 2) void net_main(
    const float* __restrict__ x,
    const float* __restrict__ W1, const float* __restrict__ b1,
    const float* __restrict__ W2, const float* __restrict__ b2,
    const float* __restrict__ W3, const float* __restrict__ b3,
    float* __restrict__ out,
    float* __restrict__ t_part, int* __restrict__ c_part,
    unsigned* __restrict__ counter,
    int half, int nrows, double inv_denom)
{
    const int tid = threadIdx.x;
    const int r0  = blockIdx.x * TPB + tid;

    float t_acc = 0.0f;
    int   s_cnt = 0;

    if (r0 < half) {
        const int r1 = r0 + half;
        const float2 xa = reinterpret_cast<const float2*>(x)[r0];
        const float2 xb = reinterpret_cast<const float2*>(x)[r1];

        // ---- layer 1 for both rows (small, one-time: scalar path is fine) ----
        float A[32], B[32];
#pragma unroll
        for (int j = 0; j < 32; ++j) {
            const float w0 = W1[2 * j], w1 = W1[2 * j + 1], bb = b1[j];
            A[j] = fmaf(xa.y, w1, fmaf(xa.x, w0, bb));
            B[j] = fmaf(xb.y, w1, fmaf(xb.x, w0, bb));
        }

        partial_act(A, t_acc, s_cnt);
        partial_act(B, t_acc, s_cnt);

        // ---- layer 2, j-outer; W2 via divergent-faked VMEM float4 loads ----
        int zero;
        asm volatile("v_mov_b32 %0, 0" : "=v"(zero));  // opaque 0: forces VMEM
        const float4* W2v = reinterpret_cast<const float4*>(W2 + zero);

        float ZA[32], ZB[32];
#pragma unroll
        for (int j = 0; j < 32; ++j) {
            float a0 = b2[j];
            float a1 = b2[j];
#pragma unroll
            for (int q = 0; q < 8; ++q) {
                const float4 w = W2v[j * 8 + q];  // global_load_dwordx4, L1 hit
                a0 = fmaf(A[4 * q],     w.x, a0); // ascending-k chain: exact
                a1 = fmaf(B[4 * q],     w.x, a1); //  same order as rounds 2/3/6
                a0 = fmaf(A[4 * q + 1], w.y, a0);
                a1 = fmaf(B[4 * q + 1], w.y, a1);
                a0 = fmaf(A[4 * q + 2], w.z, a0);
                a1 = fmaf(B[4 * q + 2], w.z, a1);
                a0 = fmaf(A[4 * q + 3], w.w, a0);
                a1 = fmaf(B[4 * q + 3], w.w, a1);
            }
            ZA[j] = a0;
            ZB[j] = a1;
        }

        partial_act(ZA, t_acc, s_cnt);
        partial_act(ZB, t_acc, s_cnt);

        // ---- layer 3 + softmax, both rows ----
        {
            float z0 = b3[0], z1 = b3[1];
            float y0 = b3[0], y1 = b3[1];
#pragma unroll
            for (int k = 0; k < 32; ++k) {
                const float wa = W3[k], wb = W3[32 + k];
                z0 = fmaf(ZA[k], wa, z0);
                z1 = fmaf(ZA[k], wb, z1);
                y0 = fmaf(ZB[k], wa, y0);
                y1 = fmaf(ZB[k], wb, y1);
            }
            float m0  = fmaxf(z0, z1);
            float e00 = __expf(z0 - m0);
            float e01 = __expf(z1 - m0);
            float i0  = 1.0f / (e00 + e01);
            float2 oa; oa.x = e00 * i0; oa.y = e01 * i0;
            reinterpret_cast<float2*>(out)[r0] = oa;

            float m1  = fmaxf(y0, y1);
            float e10 = __expf(y0 - m1);
            float e11 = __expf(y1 - m1);
            float i1  = 1.0f / (e10 + e11);
            float2 ob; ob.x = e10 * i1; ob.y = e11 * i1;
            reinterpret_cast<float2*>(out)[r1] = ob;
        }
    }

    // ---- block reduction: wave shuffle -> LDS -> per-block partial ----
#pragma unroll
    for (int off = 32; off; off >>= 1) {
        t_acc += __shfl_down(t_acc, off);
        s_cnt += __shfl_down(s_cnt, off);
    }
    __shared__ float ts[TPB / 64];
    __shared__ int   cs[TPB / 64];
    __shared__ bool  amLast;
    const int wid  = tid >> 6;
    const int lane = tid & 63;
    if (lane == 0) { ts[wid] = t_acc; cs[wid] = s_cnt; }
    __syncthreads();
    if (tid == 0) {
        float tt = ts[0];
        int   cc = cs[0];
#pragma unroll
        for (int w = 1; w < TPB / 64; ++w) { tt += ts[w]; cc += cs[w]; }
        t_part[blockIdx.x] = tt;
        c_part[blockIdx.x] = cc;
        __threadfence();                        // partials visible device-wide
        unsigned old = atomicAdd(counter, 1u);  // device-scope by default
        amLast = (old == gridDim.x - 1);
    }
    __syncthreads();

    // ---- last block reduces all partials (fixed order -> deterministic) ----
    if (amLast) {
        __threadfence();
        double t = 0.0;
        int    c = 0;
        const int nparts = gridDim.x;
        for (int i = tid; i < nparts; i += TPB) {
            t += (double)t_part[i];
            c += c_part[i];
        }
#pragma unroll
        for (int off = 32; off; off >>= 1) {
            t += __shfl_down(t, off);
            c += __shfl_down(c, off);
        }
        __shared__ double td[TPB / 64];
        __shared__ int    cd[TPB / 64];
        if (lane == 0) { td[wid] = t; cd[wid] = c; }
        __syncthreads();
        if (tid == 0) {
            double tt = 0.0;
            int    cc = 0;
#pragma unroll
            for (int w = 0; w < TPB / 64; ++w) { tt += td[w]; cc += cd[w]; }
            float* scal = out + (size_t)nrows * 2;
            scal[0] = (float)((double)cc * inv_denom); // succ = cnt / (2B)
            scal[1] = (float)tt;                       // train = t1 + t2
        }
    }
}

extern "C" void kernel_launch(void* const* d_in, const int* in_sizes, int n_in,
                              void* d_out, int out_size, void* d_ws, size_t ws_size,
                              hipStream_t stream)
{
    const float* x  = (const float*)d_in[0];
    const float* W1 = (const float*)d_in[1];
    const float* b1 = (const float*)d_in[2];
    const float* W2 = (const float*)d_in[3];
    const float* b2 = (const float*)d_in[4];
    const float* W3 = (const float*)d_in[5];
    const float* b3 = (const float*)d_in[6];
    float* out = (float*)d_out;

    const int nrows   = in_sizes[0] / 2;          // B = 1048576
    const int half    = nrows / 2;                // 2 rows per thread
    const int nblocks = (half + TPB - 1) / TPB;   // 2048

    float*    t_part  = (float*)d_ws;
    int*      c_part  = (int*)((char*)d_ws + (size_t)nblocks * sizeof(float));
    unsigned* counter = (unsigned*)((char*)d_ws + (size_t)nblocks * 2 * sizeof(float));

    // ws is poisoned 0xAA before every timed launch -> zero the done-counter.
    hipMemsetAsync(counter, 0, sizeof(unsigned), stream);

    net_main<<<nblocks, TPB, 0, stream>>>(x, W1, b1, W2, b2, W3, b3,
                                          out, t_part, c_part, counter,
                                          half, nrows, 1.0 / (2.0 * (double)nrows));
}

// Round 9
// 158.779 us; speedup vs baseline: 1.9401x; 1.2747x over previous
//
#include <hip/hip_runtime.h>

#define TPB 256

typedef float f32x2 __attribute__((ext_vector_type(2)));

// ---------------------------------------------------------------------------
// v_pk_fma_f32: one instruction, two independent f32 FMA chains (lo/hi half).
// Weight comes from an SGPR PAIR (double) with op_sel broadcasting one half
// to both lanes -> no duplication movs, 1 scalar operand per instr (legal).
// pkfma_lo: acc.{lo,hi} += ab.{lo,hi} * w.lo
// pkfma_hi: acc.{lo,hi} += ab.{lo,hi} * w.hi
// Each half keeps its own exact ascending-k chain -> bit-identical numerics
// to the scalar version in rounds 2/3/6/8 (all passed, absmax 0.0039).
// ---------------------------------------------------------------------------
__device__ __forceinline__ void pkfma_lo(f32x2& acc, f32x2 ab, double w) {
    asm("v_pk_fma_f32 %0, %1, %2, %0 op_sel:[0,0,0] op_sel_hi:[1,0,1]"
        : "+v"(acc) : "v"(ab), "s"(w));
}
__device__ __forceinline__ void pkfma_hi(f32x2& acc, f32x2 ab, double w) {
    asm("v_pk_fma_f32 %0, %1, %2, %0 op_sel:[0,1,0] op_sel_hi:[1,1,1]"
        : "+v"(acc) : "v"(ab), "s"(w));
}

// ---------------------------------------------------------------------------
// partial_activation on one half (H=0: row A, H=1: row B) of the packed
// state. Identical op sequence to the scalar version of rounds 2/3/6/8 --
// do NOT reassociate: mask decisions are sign-sensitive. All indices are
// compile-time constants (rule #20).
// ---------------------------------------------------------------------------
template<int H>
__device__ __forceinline__ void partial_act_h(f32x2 (&Y)[32], float& t_acc, int& s_cnt)
{
    int pos[16];
#pragma unroll
    for (int b = 0; b < 16; ++b)
        pos[b] = (Y[2 * b][H] > 0.0f ? 1 : 0) + (Y[2 * b + 1][H] > 0.0f ? 1 : 0);

    int minv = pos[0], maxv = pos[0];
    int minI = 0, maxI = 0;
    float ymin0 = Y[0][H], ymin1 = Y[1][H];
    float ymax0 = Y[0][H], ymax1 = Y[1][H];
#pragma unroll
    for (int b = 1; b < 16; ++b) {
        bool lt = pos[b] < minv;   // strict < keeps FIRST argmin (jnp.argmin)
        minv  = lt ? pos[b]          : minv;
        minI  = lt ? b               : minI;
        ymin0 = lt ? Y[2 * b][H]     : ymin0;
        ymin1 = lt ? Y[2 * b + 1][H] : ymin1;
        bool gt = pos[b] > maxv;   // strict > keeps FIRST argmax (jnp.argmax)
        maxv  = gt ? pos[b]          : maxv;
        maxI  = gt ? b               : maxI;
        ymax0 = gt ? Y[2 * b][H]     : ymax0;
        ymax1 = gt ? Y[2 * b + 1][H] : ymax1;
    }
    bool min_succ = (minv == 0);
    bool max_succ = (maxv == 2);

    // train uses PRE-mask Y: y*(y>0)==max(y,0); -y*(y<0)==-min(y,0)
    float cmin = fmaxf(ymin0, 0.0f) + fmaxf(ymin1, 0.0f);
    float cmax = -(fminf(ymax0, 0.0f) + fminf(ymax1, 0.0f));
    t_acc += (min_succ ? 0.0f : cmin) + (max_succ ? 0.0f : cmax);
    s_cnt += (min_succ && max_succ) ? 1 : 0;

#pragma unroll
    for (int b = 0; b < 16; ++b) {
        bool ismax = max_succ && (b == maxI);
        bool ismin = min_succ && (b == minI);
        float mfac = ismax ? 2.0f : 1.0f;
        mfac = ismin ? 0.0f : mfac;
        Y[2 * b][H]     *= mfac;
        Y[2 * b + 1][H] *= mfac;
    }
}

// ---------------------------------------------------------------------------
// Round-9: R6 anchor structure (R=2 rows/thread, j-outer, SGPR weight
// delivery -- the only free broadcast path) with two issue-count fixes:
//  (1) __launch_bounds__(256,2): R6's VGPR_Count=72 with 128+ live floats and
//      no scratch traffic implies AGPR parking + accvgpr shuffles on every
//      access (the hidden 2x busy-time). Cap 256 keeps state in real VGPRs.
//  (2) layers 2/3 use v_pk_fma_f32: both rows' chains in one instr (2048 ->
//      1024 + 128 -> 64), numerics bit-identical per half.
// ---------------------------------------------------------------------------
__global__ __launch_bounds__(TPB, 2) void net_main(
    const float* __restrict__ x,
    const float* __restrict__ W1, const float* __restrict__ b1,
    const float* __restrict__ W2, const float* __restrict__ b2,
    const float* __restrict__ W3, const float* __restrict__ b3,
    float* __restrict__ out,
    float* __restrict__ t_part, int* __restrict__ c_part,
    unsigned* __restrict__ counter,
    int half, int nrows, double inv_denom)
{
    const int tid = threadIdx.x;
    const int r0  = blockIdx.x * TPB + tid;

    float t_acc = 0.0f;
    int   s_cnt = 0;

    if (r0 < half) {
        const int r1 = r0 + half;
        const float2 xa = reinterpret_cast<const float2*>(x)[r0];
        const float2 xb = reinterpret_cast<const float2*>(x)[r1];

        // ---- layer 1 for both rows, writing packed halves (lo=row0, hi=row1) ----
        f32x2 AB[32];
#pragma unroll
        for (int j = 0; j < 32; ++j) {
            const float w0 = W1[2 * j], w1 = W1[2 * j + 1], bb = b1[j];
            AB[j][0] = fmaf(xa.y, w1, fmaf(xa.x, w0, bb));
            AB[j][1] = fmaf(xb.y, w1, fmaf(xb.x, w0, bb));
        }

        partial_act_h<0>(AB, t_acc, s_cnt);
        partial_act_h<1>(AB, t_acc, s_cnt);

        // ---- layer 2, j-outer, packed: per k one v_pk_fma does both rows.
        //      Weights stream as doubles (w[2q],w[2q+1]) into SGPR pairs. ----
        const double* W2d = reinterpret_cast<const double*>(W2);
        f32x2 ZAB[32];
#pragma unroll
        for (int j = 0; j < 32; ++j) {
            f32x2 acc;
            acc[0] = b2[j];
            acc[1] = b2[j];
#pragma unroll
            for (int q = 0; q < 16; ++q) {
                const double wd = W2d[j * 16 + q];   // W2[j][2q], W2[j][2q+1]
                pkfma_lo(acc, AB[2 * q],     wd);    // k = 2q   (ascending-k
                pkfma_hi(acc, AB[2 * q + 1], wd);    // k = 2q+1  chain kept)
            }
            ZAB[j] = acc;
        }

        partial_act_h<0>(ZAB, t_acc, s_cnt);
        partial_act_h<1>(ZAB, t_acc, s_cnt);

        // ---- layer 3 packed (z0/z1 each hold both rows) + softmax ----
        const double* W3d = reinterpret_cast<const double*>(W3);
        f32x2 z0, z1;
        z0[0] = b3[0]; z0[1] = b3[0];
        z1[0] = b3[1]; z1[1] = b3[1];
#pragma unroll
        for (int q = 0; q < 16; ++q) {
            const double wa = W3d[q];        // W3[0][2q], W3[0][2q+1]
            pkfma_lo(z0, ZAB[2 * q],     wa);
            pkfma_hi(z0, ZAB[2 * q + 1], wa);
            const double wb = W3d[16 + q];   // W3[1][2q], W3[1][2q+1]
            pkfma_lo(z1, ZAB[2 * q],     wb);
            pkfma_hi(z1, ZAB[2 * q + 1], wb);
        }
        {
            float m0  = fmaxf(z0[0], z1[0]);
            float e00 = __expf(z0[0] - m0);
            float e01 = __expf(z1[0] - m0);
            float i0  = 1.0f / (e00 + e01);
            float2 oa; oa.x = e00 * i0; oa.y = e01 * i0;
            reinterpret_cast<float2*>(out)[r0] = oa;

            float m1  = fmaxf(z0[1], z1[1]);
            float e10 = __expf(z0[1] - m1);
            float e11 = __expf(z1[1] - m1);
            float i1  = 1.0f / (e10 + e11);
            float2 ob; ob.x = e10 * i1; ob.y = e11 * i1;
            reinterpret_cast<float2*>(out)[r1] = ob;
        }
    }

    // ---- block reduction: wave shuffle -> LDS -> per-block partial ----
#pragma unroll
    for (int off = 32; off; off >>= 1) {
        t_acc += __shfl_down(t_acc, off);
        s_cnt += __shfl_down(s_cnt, off);
    }
    __shared__ float ts[TPB / 64];
    __shared__ int   cs[TPB / 64];
    __shared__ bool  amLast;
    const int wid  = tid >> 6;
    const int lane = tid & 63;
    if (lane == 0) { ts[wid] = t_acc; cs[wid] = s_cnt; }
    __syncthreads();
    if (tid == 0) {
        float tt = ts[0];
        int   cc = cs[0];
#pragma unroll
        for (int w = 1; w < TPB / 64; ++w) { tt += ts[w]; cc += cs[w]; }
        t_part[blockIdx.x] = tt;
        c_part[blockIdx.x] = cc;
        __threadfence();                        // partials visible device-wide
        unsigned old = atomicAdd(counter, 1u);  // device-scope by default
        amLast = (old == gridDim.x - 1);
    }
    __syncthreads();

    // ---- last block reduces all partials (fixed order -> deterministic) ----
    if (amLast) {
        __threadfence();
        double t = 0.0;
        int    c = 0;
        const int nparts = gridDim.x;
        for (int i = tid; i < nparts; i += TPB) {
            t += (double)t_part[i];
            c += c_part[i];
        }
#pragma unroll
        for (int off = 32; off; off >>= 1) {
            t += __shfl_down(t, off);
            c += __shfl_down(c, off);
        }
        __shared__ double td[TPB / 64];
        __shared__ int    cd[TPB / 64];
        if (lane == 0) { td[wid] = t; cd[wid] = c; }
        __syncthreads();
        if (tid == 0) {
            double tt = 0.0;
            int    cc = 0;
#pragma unroll
            for (int w = 0; w < TPB / 64; ++w) { tt += td[w]; cc += cd[w]; }
            float* scal = out + (size_t)nrows * 2;
            scal[0] = (float)((double)cc * inv_denom); // succ = cnt / (2B)
            scal[1] = (float)tt;                       // train = t1 + t2
        }
    }
}

extern "C" void kernel_launch(void* const* d_in, const int* in_sizes, int n_in,
                              void* d_out, int out_size, void* d_ws, size_t ws_size,
                              hipStream_t stream)
{
    const float* x  = (const float*)d_in[0];
    const float* W1 = (const float*)d_in[1];
    const float* b1 = (const float*)d_in[2];
    const float* W2 = (const float*)d_in[3];
    const float* b2 = (const float*)d_in[4];
    const float* W3 = (const float*)d_in[5];
    const float* b3 = (const float*)d_in[6];
    float* out = (float*)d_out;

    const int nrows   = in_sizes[0] / 2;          // B = 1048576
    const int half    = nrows / 2;                // 2 rows per thread
    const int nblocks = (half + TPB - 1) / TPB;   // 2048

    float*    t_part  = (float*)d_ws;
    int*      c_part  = (int*)((char*)d_ws + (size_t)nblocks * sizeof(float));
    unsigned* counter = (unsigned*)((char*)d_ws + (size_t)nblocks * 2 * sizeof(float));

    // ws is poisoned 0xAA before every timed launch -> zero the done-counter.
    hipMemsetAsync(counter, 0, sizeof(unsigned), stream);

    net_main<<<nblocks, TPB, 0, stream>>>(x, W1, b1, W2, b2, W3, b3,
                                          out, t_part, c_part, counter,
                                          half, nrows, 1.0 / (2.0 * (double)nrows));
}